// Round 1
// baseline (3516.188 us; speedup 1.0000x reference)
//
#include <hip/hip_runtime.h>
#include <math.h>

typedef float f32x4 __attribute__((ext_vector_type(4)));
typedef short s16x8 __attribute__((ext_vector_type(8)));
typedef unsigned short u16;

#define DI __device__ __forceinline__

// ---------- scalar helpers ----------
DI float bf2f(u16 h) { union { unsigned u; float f; } v; v.u = ((unsigned)h) << 16; return v.f; }
DI u16 f2bf(float f) {
  union { float f; unsigned u; } v; v.f = f;
  unsigned u = v.u;
  u += 0x7FFFu + ((u >> 16) & 1u);   // RNE
  return (u16)(u >> 16);
}
DI float tanh_fast(float x) {        // 1 - 2/(e^{2x}+1); saturates correctly at +-inf
  float e = __expf(2.f * x);
  return 1.f - 2.f / (e + 1.f);
}
DI float sigmoid_f(float x) { return 1.f / (1.f + __expf(-x)); }
DI float softplus_f(float x) { return fmaxf(x, 0.f) + log1pf(__expf(-fabsf(x))); }
DI f32x4 mfma16(s16x8 a, s16x8 b, f32x4 c) {
  return __builtin_amdgcn_mfma_f32_16x16x32_bf16(a, b, c, 0, 0, 0);
}

// ---------- ws layout (u16 units) ----------
// B-fragment packs: tile = 64 lanes x 8 bf16 = 512 u16.  tile index = kt*NT + nt.
// B[k][n] = W[n][k]  (y = x @ W.T)
static constexpr size_t U_RNN = 0;          // Whh_b : KT=13 NT=28 (364 tiles)
static constexpr size_t U_C1  = 186368;     // Wc    : KT=4  NT=28 (112)
static constexpr size_t U_C2  = 243712;     // Wmu|Wsig : KT=13 NT=14 (182)
static constexpr size_t U_GA  = 336896;     // Wg1|Wh1  : KT=4  NT=28 (112)
static constexpr size_t U_GB  = 394240;     // Wg2|Wh2  : KT=7  NT=14 (98)
static constexpr size_t U_GC  = 444416;     // Wmg|Wsg  : KT=4  NT=14 (56)
static constexpr size_t U_E1  = 473088;     // We1 : KT=4 NT=7  (28)
static constexpr size_t U_E2  = 487424;     // We2 : KT=4 NT=7  (28)
static constexpr size_t U_E3  = 501760;     // We3 : KT=4 NT=6  (24)
static constexpr size_t U_IN  = 514048;     // Wih_b: KT=3 NT=25 (75)
static constexpr size_t U_XB  = 552448;     // xb bf16 [S=256][B=128][400]
static constexpr size_t U_HR  = 13659648;   // h_right bf16 [256][128][400]
// end = 26,766,848 u16 = 53,533,696 bytes

// ---------- K0: pack all weight matrices into MFMA B-fragment order ----------
__global__ void k_pack(u16* __restrict__ ws,
    const float* __restrict__ Whh_b, const float* __restrict__ Wc,
    const float* __restrict__ Wmu, const float* __restrict__ Wsig,
    const float* __restrict__ Wg1, const float* __restrict__ Wh1,
    const float* __restrict__ Wg2, const float* __restrict__ Wh2,
    const float* __restrict__ Wmg, const float* __restrict__ Wsg,
    const float* __restrict__ We1, const float* __restrict__ We2,
    const float* __restrict__ We3, const float* __restrict__ Wih_b)
{
  int r = blockIdx.x, l = threadIdx.x;
  int region, local;
  if      (r < 364)  { region = 0; local = r; }
  else if (r < 476)  { region = 1; local = r - 364; }
  else if (r < 658)  { region = 2; local = r - 476; }
  else if (r < 770)  { region = 3; local = r - 658; }
  else if (r < 868)  { region = 4; local = r - 770; }
  else if (r < 924)  { region = 5; local = r - 868; }
  else if (r < 952)  { region = 6; local = r - 924; }
  else if (r < 980)  { region = 7; local = r - 952; }
  else if (r < 1004) { region = 8; local = r - 980; }
  else               { region = 9; local = r - 1004; }

  int NT; size_t base;
  switch (region) {
    case 0: NT = 28; base = U_RNN; break;
    case 1: NT = 28; base = U_C1;  break;
    case 2: NT = 14; base = U_C2;  break;
    case 3: NT = 28; base = U_GA;  break;
    case 4: NT = 14; base = U_GB;  break;
    case 5: NT = 14; base = U_GC;  break;
    case 6: NT = 7;  base = U_E1;  break;
    case 7: NT = 7;  base = U_E2;  break;
    case 8: NT = 6;  base = U_E3;  break;
    default:NT = 25; base = U_IN;  break;
  }
  int kt = local / NT, nt = local % NT;
  u16* out = ws + base + ((size_t)local * 64 + l) * 8;
  #pragma unroll
  for (int e = 0; e < 8; ++e) {
    int k = kt * 32 + (l >> 4) * 8 + e;
    int n = nt * 16 + (l & 15);
    float v = 0.f;
    switch (region) {
      case 0: if (n < 400 && k < 400) v = Whh_b[n * 400 + k]; break;
      case 1: if (n < 400 && k < 100) v = Wc[n * 100 + k]; break;
      case 2: if (n < 112) { if (n < 100 && k < 400) v = Wmu[n * 400 + k]; }
              else { int m = n - 112; if (m < 100 && k < 400) v = Wsig[m * 400 + k]; } break;
      case 3: if (n < 208) { if (n < 200 && k < 100) v = Wg1[n * 100 + k]; }
              else if (n < 416) { int m = n - 208; if (m < 200 && k < 100) v = Wh1[m * 100 + k]; } break;
      case 4: if (n < 112) { if (n < 100 && k < 200) v = Wg2[n * 200 + k]; }
              else { int m = n - 112; if (m < 100 && k < 200) v = Wh2[m * 200 + k]; } break;
      case 5: if (n < 112) { if (n < 100 && k < 100) v = Wmg[n * 100 + k]; }
              else { int m = n - 112; if (m < 100 && k < 100) v = Wsg[m * 100 + k]; } break;
      case 6: if (n < 100 && k < 100) v = We1[n * 100 + k]; break;
      case 7: if (n < 100 && k < 100) v = We2[n * 100 + k]; break;
      case 8: if (n < 88  && k < 100) v = We3[n * 100 + k]; break;
      default:if (n < 400 && k < 88)  v = Wih_b[n * 88 + k]; break;
    }
    out[e] = f2bf(v);
  }
}

// ---------- K1: xb[s][b][i] = x[b][s][:] @ Wih_b.T + bih_b  (bf16 out) ----------
__global__ __launch_bounds__(256) void k_proj(
    const float* __restrict__ x, const float* __restrict__ bih_b,
    const u16* __restrict__ pk_in, u16* __restrict__ xb)
{
  __shared__ __align__(16) u16 x_lds[16][104];   // stride 104 u16 (208B = 16*13)
  const int tid = threadIdx.x;
  const int c = blockIdx.x;                      // chunk of 16 (b,s)-rows
  const int b = c >> 4, s0 = (c & 15) << 4;
  const float* xg = x + (size_t)c * 16 * 88;
  for (int idx = tid; idx < 16 * 104; idx += 256) {
    int r = idx / 104, k = idx % 104;
    x_lds[r][k] = (k < 88) ? f2bf(xg[r * 88 + k]) : (u16)0;
  }
  __syncthreads();
  const int w = tid >> 6, l = tid & 63, g = l >> 4, li = l & 15;
  s16x8 a[3];
  #pragma unroll
  for (int kt = 0; kt < 3; ++kt)
    a[kt] = *(const s16x8*)&x_lds[li][kt * 32 + g * 8];
  for (int nt = w; nt < 25; nt += 4) {
    f32x4 acc = (f32x4){0.f, 0.f, 0.f, 0.f};
    #pragma unroll
    for (int kt = 0; kt < 3; ++kt) {
      s16x8 bfr = *(const s16x8*)(pk_in + ((size_t)(kt * 25 + nt) * 64 + l) * 8);
      acc = mfma16(a[kt], bfr, acc);
    }
    int i = nt * 16 + li;
    float bias = bih_b[i];
    #pragma unroll
    for (int q = 0; q < 4; ++q) {
      int r = g * 4 + q;
      xb[((size_t)(s0 + r) * 128 + b) * 400 + i] = f2bf(acc[q] + bias);
    }
  }
}

// ---------- K2: fused backward-RNN (blocks 0-7) + generative scan (blocks 8-15) ----------
__global__ __launch_bounds__(448, 2) void k_scan(
    const u16* __restrict__ pk_rnn, const u16* __restrict__ pk_gA,
    const u16* __restrict__ pk_gB, const u16* __restrict__ pk_gC,
    const u16* __restrict__ xb, u16* __restrict__ hr, const float* __restrict__ bhh_b,
    const float* __restrict__ z0g, const float* __restrict__ bg1, const float* __restrict__ bh1,
    const float* __restrict__ bg2, const float* __restrict__ bh2,
    const float* __restrict__ bmg, const float* __restrict__ bsg,
    const float* __restrict__ noise_gen, float* __restrict__ mug, float* __restrict__ sgg)
{
  __shared__ __align__(16) u16 sm[42240];        // 84,480 B
  const int tid = threadIdx.x;
  const int w = tid >> 6, l = tid & 63, g = l >> 4, li = l & 15;
  const int bid = blockIdx.x;

  if (bid < 8) {
    // ======== backward RNN: h = tanh(xb_t + h @ Whh_b.T + bhh_b), t = 255..0 ========
    u16* slab = sm;                 // B-frags kt=11,12 : 2*28 tiles * 512 u16
    u16* hbuf = sm + 28672;         // double-buffered h : 2 * 16 * 424 u16
    for (int idx = tid; idx < 2 * 16 * 424; idx += 448) hbuf[idx] = 0;
    {
      const uint4* src = (const uint4*)(pk_rnn + (size_t)11 * 28 * 512);
      uint4* dst = (uint4*)slab;
      for (int idx = tid; idx < 3584; idx += 448) dst[idx] = src[idx];
    }
    s16x8 wf[4][11];                               // Whh frags, kt 0..10, regs
    #pragma unroll
    for (int nt_l = 0; nt_l < 4; ++nt_l) {
      int nt = w * 4 + nt_l;
      #pragma unroll
      for (int kt = 0; kt < 11; ++kt)
        wf[nt_l][kt] = *(const s16x8*)(pk_rnn + ((size_t)(kt * 28 + nt) * 64 + l) * 8);
    }
    __syncthreads();
    const int b0 = bid * 16;
    int cur = 0;
    for (int t = 0; t < 256; ++t) {
      const int tt = 255 - t;
      f32x4 acc[4];
      #pragma unroll
      for (int i = 0; i < 4; ++i) acc[i] = (f32x4){0.f, 0.f, 0.f, 0.f};
      const u16* hb = hbuf + cur * (16 * 424);
      #pragma unroll
      for (int kt = 0; kt < 13; ++kt) {
        s16x8 a = *(const s16x8*)(hb + li * 424 + kt * 32 + g * 8);
        if (kt < 11) {
          #pragma unroll
          for (int nt_l = 0; nt_l < 4; ++nt_l) acc[nt_l] = mfma16(a, wf[nt_l][kt], acc[nt_l]);
        } else {
          #pragma unroll
          for (int nt_l = 0; nt_l < 4; ++nt_l) {
            s16x8 bfr = *(const s16x8*)(slab + ((size_t)((kt - 11) * 28 + w * 4 + nt_l) * 64 + l) * 8);
            acc[nt_l] = mfma16(a, bfr, acc[nt_l]);
          }
        }
      }
      u16* hn = hbuf + (cur ^ 1) * (16 * 424);
      #pragma unroll
      for (int nt_l = 0; nt_l < 4; ++nt_l) {
        int i = (w * 4 + nt_l) * 16 + li;
        if (i < 400) {
          float bias = bhh_b[i];
          #pragma unroll
          for (int q = 0; q < 4; ++q) {
            int r = g * 4 + q;
            size_t off = ((size_t)tt * 128 + b0 + r) * 400 + i;
            float v = acc[nt_l][q] + bf2f(xb[off]) + bias;
            u16 hv = f2bf(tanh_fast(v));
            hn[r * 424 + i] = hv;
            hr[off] = hv;
          }
        }
      }
      __syncthreads();
      cur ^= 1;
    }
  } else {
    // ======== generative scan (tr_step) ========
    u16* zb  = sm;                      // 16*136 bf16 (z, K'=128, zero-padded)
    u16* t1b = sm + 2176;               // 16*232 bf16 (relu(z Wg1^T + bg1), K'=224)
    u16* t2b = sm + 5888;               // 16*232
    u16* rhb = sm + 9600;               // 16*136 bf16 (relu(h_prop))
    float* gb  = (float*)(sm + 11776);  // 16*112 f32 each
    float* hpb = (float*)(sm + 15360);
    float* m0b = (float*)(sm + 18944);
    float* spb = (float*)(sm + 22528);
    const int b0 = (bid - 8) * 16;
    for (int idx = tid; idx < 2176; idx += 448) {
      int r = idx / 136, c = idx % 136;
      zb[idx] = (c < 100) ? f2bf(z0g[(b0 + r) * 100 + c]) : (u16)0;
    }
    for (int idx = tid; idx < 9600; idx += 448) sm[2176 + idx] = 0;  // zero t1,t2,rh

    s16x8 wA[4][4], wB[2][7], wC[2][4];
    #pragma unroll
    for (int nt_l = 0; nt_l < 4; ++nt_l) {
      int nt = w * 4 + nt_l;
      #pragma unroll
      for (int kt = 0; kt < 4; ++kt)
        wA[nt_l][kt] = *(const s16x8*)(pk_gA + ((size_t)(kt * 28 + nt) * 64 + l) * 8);
    }
    #pragma unroll
    for (int nt_l = 0; nt_l < 2; ++nt_l) {
      int nt = w * 2 + nt_l;
      #pragma unroll
      for (int kt = 0; kt < 7; ++kt)
        wB[nt_l][kt] = *(const s16x8*)(pk_gB + ((size_t)(kt * 14 + nt) * 64 + l) * 8);
      #pragma unroll
      for (int kt = 0; kt < 4; ++kt)
        wC[nt_l][kt] = *(const s16x8*)(pk_gC + ((size_t)(kt * 14 + nt) * 64 + l) * 8);
    }
    __syncthreads();

    for (int t = 0; t < 256; ++t) {
      { // ph1: t1 = relu(z Wg1^T + bg1), t2 = relu(z Wh1^T + bh1)
        f32x4 acc[4];
        #pragma unroll
        for (int i = 0; i < 4; ++i) acc[i] = (f32x4){0.f, 0.f, 0.f, 0.f};
        s16x8 az[4];
        #pragma unroll
        for (int kt = 0; kt < 4; ++kt)
          az[kt] = *(const s16x8*)(zb + li * 136 + kt * 32 + g * 8);
        #pragma unroll
        for (int kt = 0; kt < 4; ++kt) {
          #pragma unroll
          for (int nt_l = 0; nt_l < 4; ++nt_l) acc[nt_l] = mfma16(az[kt], wA[nt_l][kt], acc[nt_l]);
        }
        #pragma unroll
        for (int nt_l = 0; nt_l < 4; ++nt_l) {
          int n = (w * 4 + nt_l) * 16 + li;
          if (n < 416) {
            bool is1 = n < 208;
            int j = is1 ? n : n - 208;
            u16* dst = is1 ? t1b : t2b;
            float bias = (j < 200) ? (is1 ? bg1[j] : bh1[j]) : 0.f;
            #pragma unroll
            for (int q = 0; q < 4; ++q)
              dst[(g * 4 + q) * 232 + j] = f2bf(fmaxf(acc[nt_l][q] + bias, 0.f));
          }
        }
      }
      __syncthreads();
      { // ph2: g = sigmoid(t1 Wg2^T + bg2) ; h_prop = t2 Wh2^T + bh2 ; rh = relu(h_prop)
        f32x4 acc[2];
        #pragma unroll
        for (int i = 0; i < 2; ++i) acc[i] = (f32x4){0.f, 0.f, 0.f, 0.f};
        #pragma unroll
        for (int nt_l = 0; nt_l < 2; ++nt_l) {
          int nt = w * 2 + nt_l;
          const u16* A = (nt < 7) ? t1b : t2b;
          #pragma unroll
          for (int kt = 0; kt < 7; ++kt) {
            s16x8 a = *(const s16x8*)(A + li * 232 + kt * 32 + g * 8);
            acc[nt_l] = mfma16(a, wB[nt_l][kt], acc[nt_l]);
          }
        }
        #pragma unroll
        for (int nt_l = 0; nt_l < 2; ++nt_l) {
          int nt = w * 2 + nt_l;
          int n = nt * 16 + li;
          if (nt < 7) {
            int c = n;
            float bias = (c < 100) ? bg2[c] : 0.f;
            #pragma unroll
            for (int q = 0; q < 4; ++q)
              gb[(g * 4 + q) * 112 + c] = sigmoid_f(acc[nt_l][q] + bias);
          } else {
            int c = n - 112;
            float bias = (c < 100) ? bh2[c] : 0.f;
            #pragma unroll
            for (int q = 0; q < 4; ++q) {
              int r = g * 4 + q;
              float v = acc[nt_l][q] + bias;
              hpb[r * 112 + c] = v;
              rhb[r * 136 + c] = f2bf(fmaxf(v, 0.f));
            }
          }
        }
      }
      __syncthreads();
      { // ph3: m0 = z Wmg^T + bmg ; sp = rh Wsg^T + bsg
        f32x4 acc[2];
        #pragma unroll
        for (int i = 0; i < 2; ++i) acc[i] = (f32x4){0.f, 0.f, 0.f, 0.f};
        #pragma unroll
        for (int nt_l = 0; nt_l < 2; ++nt_l) {
          int nt = w * 2 + nt_l;
          const u16* A = (nt < 7) ? zb : rhb;
          #pragma unroll
          for (int kt = 0; kt < 4; ++kt) {
            s16x8 a = *(const s16x8*)(A + li * 136 + kt * 32 + g * 8);
            acc[nt_l] = mfma16(a, wC[nt_l][kt], acc[nt_l]);
          }
        }
        #pragma unroll
        for (int nt_l = 0; nt_l < 2; ++nt_l) {
          int nt = w * 2 + nt_l;
          int n = nt * 16 + li;
          if (nt < 7) {
            int c = n;
            float bias = (c < 100) ? bmg[c] : 0.f;
            #pragma unroll
            for (int q = 0; q < 4; ++q) m0b[(g * 4 + q) * 112 + c] = acc[nt_l][q] + bias;
          } else {
            int c = n - 112;
            float bias = (c < 100) ? bsg[c] : 0.f;
            #pragma unroll
            for (int q = 0; q < 4; ++q) spb[(g * 4 + q) * 112 + c] = acc[nt_l][q] + bias;
          }
        }
      }
      __syncthreads();
      // ph4: mu/sigma/z update + outputs
      #pragma unroll
      for (int u = 0; u < 4; ++u) {
        int idx = tid + u * 448;
        int r = idx / 112, c = idx % 112;
        if (c < 100) {
          float gv = gb[idx], hp = hpb[idx], m0 = m0b[idx], sp = spb[idx];
          float mu = hp * gv + m0 * (1.f - gv);
          float sg = softplus_f(sp);
          float nz = noise_gen[((size_t)t * 128 + b0 + r) * 100 + c];
          zb[r * 136 + c] = f2bf(mu + sqrtf(sg) * nz);
          size_t o = ((size_t)(b0 + r) * 256 + t) * 100 + c;
          mug[o] = mu;
          sgg[o] = sg;
        }
      }
      __syncthreads();
    }
  }
}

// ---------- K3: comb scan + fused decoder ----------
__global__ __launch_bounds__(448, 2) void k_comb(
    const u16* __restrict__ pk_c1, const u16* __restrict__ pk_c2,
    const u16* __restrict__ pk_e1, const u16* __restrict__ pk_e2, const u16* __restrict__ pk_e3,
    const u16* __restrict__ hr, const float* __restrict__ bc,
    const float* __restrict__ bmu, const float* __restrict__ bsig,
    const float* __restrict__ noise_inf,
    const float* __restrict__ be1, const float* __restrict__ be2, const float* __restrict__ be3,
    float* __restrict__ mui, float* __restrict__ sgi, float* __restrict__ xh)
{
  __shared__ __align__(16) u16 sm[61440];       // 122,880 B
  u16* hb   = sm;                    // 16*424
  u16* zb   = sm + 6784;             // 16*136
  u16* e1b  = sm + 8960;             // 16*136
  u16* e2b  = sm + 11136;            // 16*136
  float* must = (float*)(sm + 13312);  // 16*112 f32
  float* vast = (float*)(sm + 16896);  // 16*112 f32
  u16* pe1 = sm + 20480;             // 28 tiles
  u16* pe2 = sm + 34816;             // 28 tiles
  u16* pe3 = sm + 49152;             // 24 tiles
  const int tid = threadIdx.x;
  const int w = tid >> 6, l = tid & 63, g = l >> 4, li = l & 15;
  const int b0 = blockIdx.x * 16;

  for (int idx = tid; idx < 13312; idx += 448) sm[idx] = 0;
  {
    uint4* d1 = (uint4*)pe1; const uint4* s1 = (const uint4*)pk_e1;
    for (int idx = tid; idx < 1792; idx += 448) d1[idx] = s1[idx];
    uint4* d2 = (uint4*)pe2; const uint4* s2 = (const uint4*)pk_e2;
    for (int idx = tid; idx < 1792; idx += 448) d2[idx] = s2[idx];
    uint4* d3 = (uint4*)pe3; const uint4* s3 = (const uint4*)pk_e3;
    for (int idx = tid; idx < 1536; idx += 448) d3[idx] = s3[idx];
  }
  s16x8 wC1[4][4], wC2[2][13];
  #pragma unroll
  for (int nt_l = 0; nt_l < 4; ++nt_l) {
    int nt = w * 4 + nt_l;
    #pragma unroll
    for (int kt = 0; kt < 4; ++kt)
      wC1[nt_l][kt] = *(const s16x8*)(pk_c1 + ((size_t)(kt * 28 + nt) * 64 + l) * 8);
  }
  #pragma unroll
  for (int nt_l = 0; nt_l < 2; ++nt_l) {
    int nt = w * 2 + nt_l;
    #pragma unroll
    for (int kt = 0; kt < 13; ++kt)
      wC2[nt_l][kt] = *(const s16x8*)(pk_c2 + ((size_t)(kt * 14 + nt) * 64 + l) * 8);
  }
  __syncthreads();

  for (int t = 0; t < 256; ++t) {
    { // ph1: h = 0.5*(tanh(z Wc^T + bc) + hr_t)
      f32x4 acc[4];
      #pragma unroll
      for (int i = 0; i < 4; ++i) acc[i] = (f32x4){0.f, 0.f, 0.f, 0.f};
      s16x8 az[4];
      #pragma unroll
      for (int kt = 0; kt < 4; ++kt)
        az[kt] = *(const s16x8*)(zb + li * 136 + kt * 32 + g * 8);
      #pragma unroll
      for (int kt = 0; kt < 4; ++kt) {
        #pragma unroll
        for (int nt_l = 0; nt_l < 4; ++nt_l) acc[nt_l] = mfma16(az[kt], wC1[nt_l][kt], acc[nt_l]);
      }
      #pragma unroll
      for (int nt_l = 0; nt_l < 4; ++nt_l) {
        int n = (w * 4 + nt_l) * 16 + li;
        if (n < 400) {
          float bias = bc[n];
          #pragma unroll
          for (int q = 0; q < 4; ++q) {
            int r = g * 4 + q;
            float hrv = bf2f(hr[((size_t)t * 128 + b0 + r) * 400 + n]);
            float hv = 0.5f * (tanh_fast(acc[nt_l][q] + bias) + hrv);
            hb[r * 424 + n] = f2bf(hv);
          }
        }
      }
    }
    __syncthreads();
    { // ph2: mu = h Wmu^T + bmu ; var = softplus(h Wsig^T + bsig); write outputs + stage
      f32x4 acc[2];
      #pragma unroll
      for (int i = 0; i < 2; ++i) acc[i] = (f32x4){0.f, 0.f, 0.f, 0.f};
      #pragma unroll
      for (int kt = 0; kt < 13; ++kt) {
        s16x8 a = *(const s16x8*)(hb + li * 424 + kt * 32 + g * 8);
        acc[0] = mfma16(a, wC2[0][kt], acc[0]);
        acc[1] = mfma16(a, wC2[1][kt], acc[1]);
      }
      #pragma unroll
      for (int nt_l = 0; nt_l < 2; ++nt_l) {
        int nt = w * 2 + nt_l;
        int n = nt * 16 + li;
        if (nt < 7) {
          int c = n;
          float bias = (c < 100) ? bmu[c] : 0.f;
          #pragma unroll
          for (int q = 0; q < 4; ++q) {
            int r = g * 4 + q;
            float mu = acc[nt_l][q] + bias;
            must[r * 112 + c] = mu;
            if (c < 100) mui[((size_t)(b0 + r) * 256 + t) * 100 + c] = mu;
          }
        } else {
          int c = n - 112;
          float bias = (c < 100) ? bsig[c] : 0.f;
          #pragma unroll
          for (int q = 0; q < 4; ++q) {
            int r = g * 4 + q;
            float va = softplus_f(acc[nt_l][q] + bias);
            vast[r * 112 + c] = va;
            if (c < 100) sgi[((size_t)(b0 + r) * 256 + t) * 100 + c] = va;
          }
        }
      }
    }
    __syncthreads();
    // ph3: z = mu + sqrt(var)*noise
    #pragma unroll
    for (int u = 0; u < 4; ++u) {
      int idx = tid + u * 448;
      int r = idx / 112, c = idx % 112;
      if (c < 100) {
        float nz = noise_inf[((size_t)t * 128 + b0 + r) * 100 + c];
        zb[r * 136 + c] = f2bf(must[idx] + sqrtf(vast[idx]) * nz);
      }
    }
    __syncthreads();
    { // ph4: e1 = relu(z We1^T + be1)
      f32x4 acc = (f32x4){0.f, 0.f, 0.f, 0.f};
      #pragma unroll
      for (int kt = 0; kt < 4; ++kt) {
        s16x8 a = *(const s16x8*)(zb + li * 136 + kt * 32 + g * 8);
        s16x8 bfr = *(const s16x8*)(pe1 + ((size_t)(kt * 7 + w) * 64 + l) * 8);
        acc = mfma16(a, bfr, acc);
      }
      int c = w * 16 + li;
      float bias = (c < 100) ? be1[c] : 0.f;
      #pragma unroll
      for (int q = 0; q < 4; ++q)
        e1b[(g * 4 + q) * 136 + c] = f2bf(fmaxf(acc[q] + bias, 0.f));
    }
    __syncthreads();
    { // ph5: e2 = relu(e1 We2^T + be2)
      f32x4 acc = (f32x4){0.f, 0.f, 0.f, 0.f};
      #pragma unroll
      for (int kt = 0; kt < 4; ++kt) {
        s16x8 a = *(const s16x8*)(e1b + li * 136 + kt * 32 + g * 8);
        s16x8 bfr = *(const s16x8*)(pe2 + ((size_t)(kt * 7 + w) * 64 + l) * 8);
        acc = mfma16(a, bfr, acc);
      }
      int c = w * 16 + li;
      float bias = (c < 100) ? be2[c] : 0.f;
      #pragma unroll
      for (int q = 0; q < 4; ++q)
        e2b[(g * 4 + q) * 136 + c] = f2bf(fmaxf(acc[q] + bias, 0.f));
    }
    __syncthreads();
    // ph6: x_hat = sigmoid(e2 We3^T + be3)
    if (w < 6) {
      f32x4 acc = (f32x4){0.f, 0.f, 0.f, 0.f};
      #pragma unroll
      for (int kt = 0; kt < 4; ++kt) {
        s16x8 a = *(const s16x8*)(e2b + li * 136 + kt * 32 + g * 8);
        s16x8 bfr = *(const s16x8*)(pe3 + ((size_t)(kt * 6 + w) * 64 + l) * 8);
        acc = mfma16(a, bfr, acc);
      }
      int n = w * 16 + li;
      if (n < 88) {
        float bias = be3[n];
        #pragma unroll
        for (int q = 0; q < 4; ++q) {
          int r = g * 4 + q;
          xh[((size_t)(b0 + r) * 256 + t) * 88 + n] = sigmoid_f(acc[q] + bias);
        }
      }
    }
    __syncthreads();
  }
}

// ---------- host ----------
extern "C" void kernel_launch(void* const* d_in, const int* in_sizes, int n_in,
                              void* d_out, int out_size, void* d_ws, size_t ws_size,
                              hipStream_t stream) {
  const float* x      = (const float*)d_in[0];
  const float* Wih_b  = (const float*)d_in[5];
  const float* Whh_b  = (const float*)d_in[6];
  const float* bih_b  = (const float*)d_in[7];
  const float* bhh_b  = (const float*)d_in[8];
  const float* Wc     = (const float*)d_in[9];
  const float* bc     = (const float*)d_in[10];
  const float* Wmu    = (const float*)d_in[11];
  const float* bmu    = (const float*)d_in[12];
  const float* Wsig   = (const float*)d_in[13];
  const float* bsig   = (const float*)d_in[14];
  const float* We1    = (const float*)d_in[15];
  const float* be1    = (const float*)d_in[16];
  const float* We2    = (const float*)d_in[17];
  const float* be2    = (const float*)d_in[18];
  const float* We3    = (const float*)d_in[19];
  const float* be3    = (const float*)d_in[20];
  const float* Wg1    = (const float*)d_in[21];
  const float* bg1    = (const float*)d_in[22];
  const float* Wg2    = (const float*)d_in[23];
  const float* bg2    = (const float*)d_in[24];
  const float* Wh1    = (const float*)d_in[25];
  const float* bh1    = (const float*)d_in[26];
  const float* Wh2    = (const float*)d_in[27];
  const float* bh2    = (const float*)d_in[28];
  const float* Wmg    = (const float*)d_in[29];
  const float* bmg    = (const float*)d_in[30];
  const float* Wsg    = (const float*)d_in[31];
  const float* bsg    = (const float*)d_in[32];
  const float* noise_inf = (const float*)d_in[33];
  const float* z0_gen    = (const float*)d_in[34];
  const float* noise_gen = (const float*)d_in[35];

  u16* ws16 = (u16*)d_ws;
  float* out = (float*)d_out;
  float* xh  = out;                 // (B,S,88)
  float* mui = out + 2883584;       // (B,S,100)
  float* sgi = out + 6160384;
  float* mug = out + 9437184;
  float* sgg = out + 12713984;

  k_pack<<<1079, 64, 0, stream>>>(ws16, Whh_b, Wc, Wmu, Wsig, Wg1, Wh1, Wg2, Wh2,
                                  Wmg, Wsg, We1, We2, We3, Wih_b);
  k_proj<<<2048, 256, 0, stream>>>(x, bih_b, ws16 + U_IN, ws16 + U_XB);
  k_scan<<<16, 448, 0, stream>>>(ws16 + U_RNN, ws16 + U_GA, ws16 + U_GB, ws16 + U_GC,
                                 ws16 + U_XB, ws16 + U_HR, bhh_b,
                                 z0_gen, bg1, bh1, bg2, bh2, bmg, bsg, noise_gen, mug, sgg);
  k_comb<<<8, 448, 0, stream>>>(ws16 + U_C1, ws16 + U_C2, ws16 + U_E1, ws16 + U_E2, ws16 + U_E3,
                                ws16 + U_HR, bc, bmu, bsig, noise_inf, be1, be2, be3,
                                mui, sgi, xh);
}

// Round 2
// 2069.987 us; speedup vs baseline: 1.6987x; 1.6987x over previous
//
#include <hip/hip_runtime.h>
#include <math.h>

typedef float f32x4 __attribute__((ext_vector_type(4)));
typedef short s16x8 __attribute__((ext_vector_type(8)));
typedef unsigned short u16;

#define DI __device__ __forceinline__

// ---------- scalar helpers ----------
DI float bf2f(u16 h) { union { unsigned u; float f; } v; v.u = ((unsigned)h) << 16; return v.f; }
DI u16 f2bf(float f) {
  union { float f; unsigned u; } v; v.f = f;
  unsigned u = v.u;
  u += 0x7FFFu + ((u >> 16) & 1u);   // RNE
  return (u16)(u >> 16);
}
DI float tanh_fast(float x) {
  float e = __expf(2.f * x);
  return 1.f - 2.f / (e + 1.f);
}
DI float sigmoid_f(float x) { return 1.f / (1.f + __expf(-x)); }
DI float softplus_f(float x) { return fmaxf(x, 0.f) + log1pf(__expf(-fabsf(x))); }
DI f32x4 mfma16(s16x8 a, s16x8 b, f32x4 c) {
  return __builtin_amdgcn_mfma_f32_16x16x32_bf16(a, b, c, 0, 0, 0);
}
// Barrier with LDS drain only (no vmcnt drain): global stores are fire-and-forget,
// prefetch loads stay in flight across the barrier.
DI void bar_lds() { asm volatile("s_waitcnt lgkmcnt(0)\n\ts_barrier" ::: "memory"); }

// ---------- ws layout (u16 units) ----------
static constexpr size_t U_RNN = 0;          // Whh_b : KT=13 NT=28 (364 tiles)
static constexpr size_t U_C1  = 186368;     // Wc    : KT=4  NT=28 (112)
static constexpr size_t U_C2  = 243712;     // Wmu|Wsig : KT=13 NT=14 (182)
static constexpr size_t U_GA  = 336896;     // Wg1|Wh1  : KT=4  NT=28 (112)
static constexpr size_t U_GB  = 394240;     // Wg2|Wh2  : KT=7  NT=14 (98)
static constexpr size_t U_GC  = 444416;     // Wmg|Wsg  : KT=4  NT=14 (56)
static constexpr size_t U_E1  = 473088;     // We1 : KT=4 NT=7  (28)
static constexpr size_t U_E2  = 487424;     // We2 : KT=4 NT=7  (28)
static constexpr size_t U_E3  = 501760;     // We3 : KT=4 NT=6  (24)
static constexpr size_t U_IN  = 514048;     // Wih_b: KT=3 NT=25 (75)
static constexpr size_t U_XB  = 552448;     // xb bf16 [S][B][400]; later reused as Z [B][S][112]
static constexpr size_t U_HR  = 13659648;   // h_right bf16 [256][128][400]

// ---------- K0: pack all weight matrices into MFMA B-fragment order ----------
__global__ void k_pack(u16* __restrict__ ws,
    const float* __restrict__ Whh_b, const float* __restrict__ Wc,
    const float* __restrict__ Wmu, const float* __restrict__ Wsig,
    const float* __restrict__ Wg1, const float* __restrict__ Wh1,
    const float* __restrict__ Wg2, const float* __restrict__ Wh2,
    const float* __restrict__ Wmg, const float* __restrict__ Wsg,
    const float* __restrict__ We1, const float* __restrict__ We2,
    const float* __restrict__ We3, const float* __restrict__ Wih_b)
{
  int r = blockIdx.x, l = threadIdx.x;
  int region, local;
  if      (r < 364)  { region = 0; local = r; }
  else if (r < 476)  { region = 1; local = r - 364; }
  else if (r < 658)  { region = 2; local = r - 476; }
  else if (r < 770)  { region = 3; local = r - 658; }
  else if (r < 868)  { region = 4; local = r - 770; }
  else if (r < 924)  { region = 5; local = r - 868; }
  else if (r < 952)  { region = 6; local = r - 924; }
  else if (r < 980)  { region = 7; local = r - 952; }
  else if (r < 1004) { region = 8; local = r - 980; }
  else               { region = 9; local = r - 1004; }

  int NT; size_t base;
  switch (region) {
    case 0: NT = 28; base = U_RNN; break;
    case 1: NT = 28; base = U_C1;  break;
    case 2: NT = 14; base = U_C2;  break;
    case 3: NT = 28; base = U_GA;  break;
    case 4: NT = 14; base = U_GB;  break;
    case 5: NT = 14; base = U_GC;  break;
    case 6: NT = 7;  base = U_E1;  break;
    case 7: NT = 7;  base = U_E2;  break;
    case 8: NT = 6;  base = U_E3;  break;
    default:NT = 25; base = U_IN;  break;
  }
  int kt = local / NT, nt = local % NT;
  u16* out = ws + base + ((size_t)local * 64 + l) * 8;
  #pragma unroll
  for (int e = 0; e < 8; ++e) {
    int k = kt * 32 + (l >> 4) * 8 + e;
    int n = nt * 16 + (l & 15);
    float v = 0.f;
    switch (region) {
      case 0: if (n < 400 && k < 400) v = Whh_b[n * 400 + k]; break;
      case 1: if (n < 400 && k < 100) v = Wc[n * 100 + k]; break;
      case 2: if (n < 112) { if (n < 100 && k < 400) v = Wmu[n * 400 + k]; }
              else { int m = n - 112; if (m < 100 && k < 400) v = Wsig[m * 400 + k]; } break;
      case 3: if (n < 208) { if (n < 200 && k < 100) v = Wg1[n * 100 + k]; }
              else if (n < 416) { int m = n - 208; if (m < 200 && k < 100) v = Wh1[m * 100 + k]; } break;
      case 4: if (n < 112) { if (n < 100 && k < 200) v = Wg2[n * 200 + k]; }
              else { int m = n - 112; if (m < 100 && k < 200) v = Wh2[m * 200 + k]; } break;
      case 5: if (n < 112) { if (n < 100 && k < 100) v = Wmg[n * 100 + k]; }
              else { int m = n - 112; if (m < 100 && k < 100) v = Wsg[m * 100 + k]; } break;
      case 6: if (n < 100 && k < 100) v = We1[n * 100 + k]; break;
      case 7: if (n < 100 && k < 100) v = We2[n * 100 + k]; break;
      case 8: if (n < 88  && k < 100) v = We3[n * 100 + k]; break;
      default:if (n < 400 && k < 88)  v = Wih_b[n * 88 + k]; break;
    }
    out[e] = f2bf(v);
  }
}

// ---------- K1: xb[s][b][i] = x[b][s][:] @ Wih_b.T + bih_b  (bf16 out) ----------
__global__ __launch_bounds__(256) void k_proj(
    const float* __restrict__ x, const float* __restrict__ bih_b,
    const u16* __restrict__ pk_in, u16* __restrict__ xb)
{
  __shared__ __align__(16) u16 x_lds[16][104];
  const int tid = threadIdx.x;
  const int c = blockIdx.x;
  const int b = c >> 4, s0 = (c & 15) << 4;
  const float* xg = x + (size_t)c * 16 * 88;
  for (int idx = tid; idx < 16 * 104; idx += 256) {
    int r = idx / 104, k = idx % 104;
    x_lds[r][k] = (k < 88) ? f2bf(xg[r * 88 + k]) : (u16)0;
  }
  __syncthreads();
  const int w = tid >> 6, l = tid & 63, g = l >> 4, li = l & 15;
  s16x8 a[3];
  #pragma unroll
  for (int kt = 0; kt < 3; ++kt)
    a[kt] = *(const s16x8*)&x_lds[li][kt * 32 + g * 8];
  for (int nt = w; nt < 25; nt += 4) {
    f32x4 acc = (f32x4){0.f, 0.f, 0.f, 0.f};
    #pragma unroll
    for (int kt = 0; kt < 3; ++kt) {
      s16x8 bfr = *(const s16x8*)(pk_in + ((size_t)(kt * 25 + nt) * 64 + l) * 8);
      acc = mfma16(a[kt], bfr, acc);
    }
    int i = nt * 16 + li;
    float bias = bih_b[i];
    #pragma unroll
    for (int q = 0; q < 4; ++q) {
      int r = g * 4 + q;
      xb[((size_t)(s0 + r) * 128 + b) * 400 + i] = f2bf(acc[q] + bias);
    }
  }
}

// ---------- K2: fused backward-RNN (blocks 0-7) + generative scan (blocks 8-15) ----------
// NOTE: __launch_bounds__ WITHOUT a min-waves arg: 448 threads = 7 waves -> the
// allocator may use up to 256 VGPRs. Round 1's (448,2) capped VGPRs at 128 and
// the compiler sank all weight fragments into the step loop (the 8.8us/step bug).
__global__ __launch_bounds__(448) void k_scan(
    const u16* __restrict__ pk_rnn, const u16* __restrict__ pk_gA,
    const u16* __restrict__ pk_gB, const u16* __restrict__ pk_gC,
    const u16* __restrict__ xb, u16* __restrict__ hr, const float* __restrict__ bhh_b,
    const float* __restrict__ z0g, const float* __restrict__ bg1, const float* __restrict__ bh1,
    const float* __restrict__ bg2, const float* __restrict__ bh2,
    const float* __restrict__ bmg, const float* __restrict__ bsg,
    const float* __restrict__ noise_gen, float* __restrict__ mug, float* __restrict__ sgg)
{
  __shared__ __align__(16) u16 sm[69120];        // 138,240 B
  const int tid = threadIdx.x;
  const int w = tid >> 6, l = tid & 63, g = l >> 4, li = l & 15;
  const int bid = blockIdx.x;

  if (bid < 8) {
    // ===== backward RNN: h = tanh(xb_t + h @ Whh_b.T + bhh_b), t = 255..0 =====
    u16* slab = sm;                  // Whh kt 10..12 : 84 tiles * 512 u16 = 43008
    u16* hbuf = sm + 43008;          // double-buffered h : 2 * 16*424
    for (int idx = tid; idx < 2 * 6784; idx += 448) hbuf[idx] = 0;
    {
      const uint4* src = (const uint4*)(pk_rnn + (size_t)10 * 28 * 512);
      uint4* dst = (uint4*)slab;
      for (int idx = tid; idx < 5376; idx += 448) dst[idx] = src[idx];
    }
    s16x8 wf[4][10];                               // Whh frags kt 0..9, per-warp nt
    #pragma unroll
    for (int nt_l = 0; nt_l < 4; ++nt_l) {
      int nt = w * 4 + nt_l;
      #pragma unroll
      for (int kt = 0; kt < 10; ++kt)
        wf[nt_l][kt] = *(const s16x8*)(pk_rnn + ((size_t)(kt * 28 + nt) * 64 + l) * 8);
    }
    bool nv[4]; float bias_r[4];
    #pragma unroll
    for (int nt_l = 0; nt_l < 4; ++nt_l) {
      int n = (w * 4 + nt_l) * 16 + li;
      nv[nt_l] = (n < 400);
      bias_r[nt_l] = nv[nt_l] ? bhh_b[n] : 0.f;
    }
    const int b0 = bid * 16;
    u16 pf[4][4];
    #pragma unroll
    for (int nt_l = 0; nt_l < 4; ++nt_l) {
      if (nv[nt_l]) {
        int n = (w * 4 + nt_l) * 16 + li;
        #pragma unroll
        for (int q = 0; q < 4; ++q)
          pf[nt_l][q] = xb[((size_t)255 * 128 + b0 + g * 4 + q) * 400 + n];
      }
    }
    __syncthreads();
    int cur = 0;
    for (int t = 0; t < 256; ++t) {
      const int tt = 255 - t;
      f32x4 acc[4];
      #pragma unroll
      for (int i = 0; i < 4; ++i) acc[i] = (f32x4){0.f, 0.f, 0.f, 0.f};
      const u16* hb = hbuf + cur * 6784;
      #pragma unroll
      for (int kt = 0; kt < 13; ++kt) {
        s16x8 a = *(const s16x8*)(hb + li * 424 + kt * 32 + g * 8);
        if (kt < 10) {
          #pragma unroll
          for (int nt_l = 0; nt_l < 4; ++nt_l) acc[nt_l] = mfma16(a, wf[nt_l][kt], acc[nt_l]);
        } else {
          #pragma unroll
          for (int nt_l = 0; nt_l < 4; ++nt_l) {
            s16x8 bfr = *(const s16x8*)(slab + ((size_t)((kt - 10) * 28 + w * 4 + nt_l) * 64 + l) * 8);
            acc[nt_l] = mfma16(a, bfr, acc[nt_l]);
          }
        }
      }
      u16* hn = hbuf + (cur ^ 1) * 6784;
      #pragma unroll
      for (int nt_l = 0; nt_l < 4; ++nt_l) {
        if (nv[nt_l]) {
          int n = (w * 4 + nt_l) * 16 + li;
          #pragma unroll
          for (int q = 0; q < 4; ++q) {
            int r = g * 4 + q;
            float v = acc[nt_l][q] + bf2f(pf[nt_l][q]) + bias_r[nt_l];
            u16 hv = f2bf(tanh_fast(v));
            hn[r * 424 + n] = hv;
            hr[((size_t)tt * 128 + b0 + r) * 400 + n] = hv;
          }
        }
      }
      if (t < 255) {     // prefetch next step's xb (in flight across the barrier)
        #pragma unroll
        for (int nt_l = 0; nt_l < 4; ++nt_l) {
          if (nv[nt_l]) {
            int n = (w * 4 + nt_l) * 16 + li;
            #pragma unroll
            for (int q = 0; q < 4; ++q)
              pf[nt_l][q] = xb[((size_t)(tt - 1) * 128 + b0 + g * 4 + q) * 400 + n];
          }
        }
      }
      bar_lds();
      cur ^= 1;
    }
  } else {
    // ===== generative scan (tr_step), 3 phases / 3 barriers per step =====
    u16* wA  = sm;                  // Wg1|Wh1 : 112 tiles = 57344 u16
    u16* t1b = sm + 57344;          // 16*232
    u16* t2b = sm + 61056;          // 16*232
    u16* zb  = sm + 64768;          // 16*136
    u16* rhb = sm + 66944;          // 16*136  (end 69120)
    const int b0 = (bid - 8) * 16;
    {
      const uint4* src = (const uint4*)pk_gA;
      uint4* dst = (uint4*)wA;
      for (int idx = tid; idx < 7168; idx += 448) dst[idx] = src[idx];
    }
    for (int idx = tid; idx < 2 * 3712; idx += 448) t1b[idx] = 0;
    for (int idx = tid; idx < 2176; idx += 448) {
      int r = idx / 136, c = idx % 136;
      zb[idx] = (c < 100) ? f2bf(z0g[(b0 + r) * 100 + c]) : (u16)0;
    }
    for (int idx = tid; idx < 2176; idx += 448) rhb[idx] = 0;

    s16x8 wBg[7], wBh[7], wCm[4], wCs[4];          // per-warp nt=w and nt=7+w
    #pragma unroll
    for (int kt = 0; kt < 7; ++kt) {
      wBg[kt] = *(const s16x8*)(pk_gB + ((size_t)(kt * 14 + w) * 64 + l) * 8);
      wBh[kt] = *(const s16x8*)(pk_gB + ((size_t)(kt * 14 + 7 + w) * 64 + l) * 8);
    }
    #pragma unroll
    for (int kt = 0; kt < 4; ++kt) {
      wCm[kt] = *(const s16x8*)(pk_gC + ((size_t)(kt * 14 + w) * 64 + l) * 8);
      wCs[kt] = *(const s16x8*)(pk_gC + ((size_t)(kt * 14 + 7 + w) * 64 + l) * 8);
    }
    const int c = w * 16 + li;
    const bool cv = (c < 100);
    const float bg2_c = cv ? bg2[c] : 0.f;
    const float bh2_c = cv ? bh2[c] : 0.f;
    const float bmg_c = cv ? bmg[c] : 0.f;
    const float bsg_c = cv ? bsg[c] : 0.f;
    float b1r[4];
    #pragma unroll
    for (int nt_l = 0; nt_l < 4; ++nt_l) {
      int n = (w * 4 + nt_l) * 16 + li;
      bool is1 = n < 208;
      int j = is1 ? n : n - 208;
      b1r[nt_l] = (n < 416 && j < 200) ? (is1 ? bg1[j] : bh1[j]) : 0.f;
    }
    float pfn[4];
    #pragma unroll
    for (int q = 0; q < 4; ++q)
      pfn[q] = cv ? noise_gen[((size_t)0 * 128 + b0 + g * 4 + q) * 100 + c] : 0.f;
    __syncthreads();

    for (int t = 0; t < 256; ++t) {
      s16x8 az[4];
      #pragma unroll
      for (int kt = 0; kt < 4; ++kt)
        az[kt] = *(const s16x8*)(zb + li * 136 + kt * 32 + g * 8);
      { // ph1: t1 = relu(z Wg1^T + bg1) ; t2 = relu(z Wh1^T + bh1)
        f32x4 a1[4];
        #pragma unroll
        for (int i = 0; i < 4; ++i) a1[i] = (f32x4){0.f, 0.f, 0.f, 0.f};
        #pragma unroll
        for (int kt = 0; kt < 4; ++kt) {
          #pragma unroll
          for (int nt_l = 0; nt_l < 4; ++nt_l) {
            s16x8 bfr = *(const s16x8*)(wA + ((size_t)(kt * 28 + w * 4 + nt_l) * 64 + l) * 8);
            a1[nt_l] = mfma16(az[kt], bfr, a1[nt_l]);
          }
        }
        #pragma unroll
        for (int nt_l = 0; nt_l < 4; ++nt_l) {
          int n = (w * 4 + nt_l) * 16 + li;
          if (n < 416) {
            bool is1 = n < 208;
            int j = is1 ? n : n - 208;
            u16* dst = is1 ? t1b : t2b;
            #pragma unroll
            for (int q = 0; q < 4; ++q)
              dst[(g * 4 + q) * 232 + j] = f2bf(fmaxf(a1[nt_l][q] + b1r[nt_l], 0.f));
          }
        }
      }
      bar_lds();
      float muq[4];
      { // ph2: g, h_prop, m0 for this warp's c-set; mu in-register; rh -> LDS
        f32x4 ag = (f32x4){0.f,0.f,0.f,0.f}, ah = ag, am = ag;
        #pragma unroll
        for (int kt = 0; kt < 7; ++kt) {
          s16x8 x1 = *(const s16x8*)(t1b + li * 232 + kt * 32 + g * 8);
          ag = mfma16(x1, wBg[kt], ag);
        }
        #pragma unroll
        for (int kt = 0; kt < 7; ++kt) {
          s16x8 x2 = *(const s16x8*)(t2b + li * 232 + kt * 32 + g * 8);
          ah = mfma16(x2, wBh[kt], ah);
        }
        #pragma unroll
        for (int kt = 0; kt < 4; ++kt) am = mfma16(az[kt], wCm[kt], am);   // reuse az regs
        #pragma unroll
        for (int q = 0; q < 4; ++q) {
          int r = g * 4 + q;
          float gv = sigmoid_f(ag[q] + bg2_c);
          float hp = ah[q] + bh2_c;
          float m0 = am[q] + bmg_c;
          muq[q] = hp * gv + m0 * (1.f - gv);
          rhb[r * 136 + c] = f2bf(fmaxf(hp, 0.f));   // zero for c>=100 (padded weights)
          if (cv) mug[((size_t)(b0 + r) * 256 + t) * 100 + c] = muq[q];
        }
      }
      bar_lds();
      { // ph3: sigma = softplus(relu(h_prop) Wsg^T + bsg) ; z update
        f32x4 as = (f32x4){0.f,0.f,0.f,0.f};
        #pragma unroll
        for (int kt = 0; kt < 4; ++kt) {
          s16x8 xr = *(const s16x8*)(rhb + li * 136 + kt * 32 + g * 8);
          as = mfma16(xr, wCs[kt], as);
        }
        #pragma unroll
        for (int q = 0; q < 4; ++q) {
          int r = g * 4 + q;
          float sg = softplus_f(as[q] + bsg_c);
          if (cv) {
            sgg[((size_t)(b0 + r) * 256 + t) * 100 + c] = sg;
            zb[r * 136 + c] = f2bf(muq[q] + sqrtf(sg) * pfn[q]);
          }
        }
      }
      if (t < 255) {
        #pragma unroll
        for (int q = 0; q < 4; ++q)
          if (cv) pfn[q] = noise_gen[((size_t)(t + 1) * 128 + b0 + g * 4 + q) * 100 + c];
      }
      bar_lds();
    }
  }
}

// ---------- K3: comb scan (2 barriers/step, decoder moved out) ----------
__global__ __launch_bounds__(448) void k_comb(
    const u16* __restrict__ pk_c1, const u16* __restrict__ pk_c2,
    const u16* __restrict__ hr, const float* __restrict__ bc,
    const float* __restrict__ bmu, const float* __restrict__ bsig,
    const float* __restrict__ noise_inf,
    u16* __restrict__ Zws, float* __restrict__ mui, float* __restrict__ sgi)
{
  __shared__ __align__(16) u16 sm[66304];       // 132,608 B
  u16* wc1 = sm;          // Wc 112 tiles = 57344 u16 (LDS-resident, warp-shared)
  u16* hb  = sm + 57344;  // 16*424
  u16* zb  = sm + 64128;  // 16*136
  const int tid = threadIdx.x;
  const int w = tid >> 6, l = tid & 63, g = l >> 4, li = l & 15;
  const int b0 = blockIdx.x * 16;

  {
    const uint4* src = (const uint4*)pk_c1;
    uint4* dst = (uint4*)wc1;
    for (int idx = tid; idx < 7168; idx += 448) dst[idx] = src[idx];
  }
  for (int idx = tid; idx < 6784 + 2176; idx += 448) hb[idx] = 0;   // hb + zb zeroed

  s16x8 wMu[13], wSg[13];                        // per-warp nt=w and nt=7+w
  #pragma unroll
  for (int kt = 0; kt < 13; ++kt) {
    wMu[kt] = *(const s16x8*)(pk_c2 + ((size_t)(kt * 14 + w) * 64 + l) * 8);
    wSg[kt] = *(const s16x8*)(pk_c2 + ((size_t)(kt * 14 + 7 + w) * 64 + l) * 8);
  }
  const int c = w * 16 + li;
  const bool cv = (c < 100);
  const float bmu_c = cv ? bmu[c] : 0.f;
  const float bsig_c = cv ? bsig[c] : 0.f;
  bool nv[4]; float bc_r[4];
  #pragma unroll
  for (int nt_l = 0; nt_l < 4; ++nt_l) {
    int n = (w * 4 + nt_l) * 16 + li;
    nv[nt_l] = (n < 400);
    bc_r[nt_l] = nv[nt_l] ? bc[n] : 0.f;
  }
  u16 pf_hr[4][4];
  #pragma unroll
  for (int nt_l = 0; nt_l < 4; ++nt_l) {
    if (nv[nt_l]) {
      int n = (w * 4 + nt_l) * 16 + li;
      #pragma unroll
      for (int q = 0; q < 4; ++q)
        pf_hr[nt_l][q] = hr[((size_t)0 * 128 + b0 + g * 4 + q) * 400 + n];
    }
  }
  float pf_nz[4];
  #pragma unroll
  for (int q = 0; q < 4; ++q)
    pf_nz[q] = cv ? noise_inf[((size_t)0 * 128 + b0 + g * 4 + q) * 100 + c] : 0.f;
  __syncthreads();

  for (int t = 0; t < 256; ++t) {
    { // ph1: h = 0.5*(tanh(z Wc^T + bc) + hr_t)
      s16x8 az[4];
      #pragma unroll
      for (int kt = 0; kt < 4; ++kt)
        az[kt] = *(const s16x8*)(zb + li * 136 + kt * 32 + g * 8);
      f32x4 a1[4];
      #pragma unroll
      for (int i = 0; i < 4; ++i) a1[i] = (f32x4){0.f, 0.f, 0.f, 0.f};
      #pragma unroll
      for (int kt = 0; kt < 4; ++kt) {
        #pragma unroll
        for (int nt_l = 0; nt_l < 4; ++nt_l) {
          s16x8 bfr = *(const s16x8*)(wc1 + ((size_t)(kt * 28 + w * 4 + nt_l) * 64 + l) * 8);
          a1[nt_l] = mfma16(az[kt], bfr, a1[nt_l]);
        }
      }
      #pragma unroll
      for (int nt_l = 0; nt_l < 4; ++nt_l) {
        if (nv[nt_l]) {
          int n = (w * 4 + nt_l) * 16 + li;
          #pragma unroll
          for (int q = 0; q < 4; ++q) {
            int r = g * 4 + q;
            float hv = 0.5f * (tanh_fast(a1[nt_l][q] + bc_r[nt_l]) + bf2f(pf_hr[nt_l][q]));
            hb[r * 424 + n] = f2bf(hv);
          }
        }
      }
      if (t < 255) {   // prefetch next hr tile
        #pragma unroll
        for (int nt_l = 0; nt_l < 4; ++nt_l) {
          if (nv[nt_l]) {
            int n = (w * 4 + nt_l) * 16 + li;
            #pragma unroll
            for (int q = 0; q < 4; ++q)
              pf_hr[nt_l][q] = hr[((size_t)(t + 1) * 128 + b0 + g * 4 + q) * 400 + n];
          }
        }
      }
    }
    bar_lds();
    { // ph2: mu / var / z, all in-register for this warp's c-set
      f32x4 am = (f32x4){0.f,0.f,0.f,0.f}, as = am;
      #pragma unroll
      for (int kt = 0; kt < 13; ++kt) {
        s16x8 a = *(const s16x8*)(hb + li * 424 + kt * 32 + g * 8);
        am = mfma16(a, wMu[kt], am);
        as = mfma16(a, wSg[kt], as);
      }
      #pragma unroll
      for (int q = 0; q < 4; ++q) {
        int r = g * 4 + q;
        float mu = am[q] + bmu_c;
        float va = softplus_f(as[q] + bsig_c);
        if (cv) {
          size_t o = ((size_t)(b0 + r) * 256 + t) * 100 + c;
          mui[o] = mu;
          sgi[o] = va;
          float z = mu + sqrtf(va) * pf_nz[q];
          zb[r * 136 + c] = f2bf(z);
          Zws[((size_t)(b0 + r) * 256 + t) * 112 + c] = f2bf(z);
        }
      }
      if (t < 255) {
        #pragma unroll
        for (int q = 0; q < 4; ++q)
          if (cv) pf_nz[q] = noise_inf[((size_t)(t + 1) * 128 + b0 + g * 4 + q) * 100 + c];
      }
    }
    bar_lds();
  }
}

// ---------- K4: decoder, parallel over (B,S) ----------
__global__ __launch_bounds__(448) void k_dec(
    const u16* __restrict__ Zws,
    const u16* __restrict__ pk_e1, const u16* __restrict__ pk_e2, const u16* __restrict__ pk_e3,
    const float* __restrict__ be1, const float* __restrict__ be2, const float* __restrict__ be3,
    float* __restrict__ xh)
{
  __shared__ __align__(16) u16 sm[3 * 2176];
  u16* zb = sm; u16* e1b = sm + 2176; u16* e2b = sm + 4352;
  const int tid = threadIdx.x;
  const int w = tid >> 6, l = tid & 63, g = l >> 4, li = l & 15;
  const int cc = blockIdx.x;
  const int b = cc >> 4, s0 = (cc & 15) << 4;

  s16x8 w1[4], w2[4], w3[4];
  #pragma unroll
  for (int kt = 0; kt < 4; ++kt) {
    w1[kt] = *(const s16x8*)(pk_e1 + ((size_t)(kt * 7 + w) * 64 + l) * 8);
    w2[kt] = *(const s16x8*)(pk_e2 + ((size_t)(kt * 7 + w) * 64 + l) * 8);
    if (w < 6) w3[kt] = *(const s16x8*)(pk_e3 + ((size_t)(kt * 6 + w) * 64 + l) * 8);
  }
  {
    const uint4* zsrc = (const uint4*)(Zws + ((size_t)b * 256 + s0) * 112);
    for (int idx = tid; idx < 224; idx += 448) {
      int r = idx / 14, cj = idx % 14;
      *(uint4*)(zb + r * 136 + cj * 8) = zsrc[idx];
    }
    for (int idx = tid; idx < 3 * 384; idx += 448) {   // zero the 24-col pads
      int bi = idx / 384, j = idx % 384;
      (sm + bi * 2176)[(j / 24) * 136 + 112 + (j % 24)] = 0;
    }
  }
  __syncthreads();
  const int c = w * 16 + li;
  { // e1 = relu(z We1^T + be1)
    f32x4 acc = (f32x4){0.f,0.f,0.f,0.f};
    #pragma unroll
    for (int kt = 0; kt < 4; ++kt) {
      s16x8 a = *(const s16x8*)(zb + li * 136 + kt * 32 + g * 8);
      acc = mfma16(a, w1[kt], acc);
    }
    float bias = (c < 100) ? be1[c] : 0.f;
    #pragma unroll
    for (int q = 0; q < 4; ++q)
      e1b[(g * 4 + q) * 136 + c] = f2bf(fmaxf(acc[q] + bias, 0.f));
  }
  bar_lds();
  { // e2 = relu(e1 We2^T + be2)
    f32x4 acc = (f32x4){0.f,0.f,0.f,0.f};
    #pragma unroll
    for (int kt = 0; kt < 4; ++kt) {
      s16x8 a = *(const s16x8*)(e1b + li * 136 + kt * 32 + g * 8);
      acc = mfma16(a, w2[kt], acc);
    }
    float bias = (c < 100) ? be2[c] : 0.f;
    #pragma unroll
    for (int q = 0; q < 4; ++q)
      e2b[(g * 4 + q) * 136 + c] = f2bf(fmaxf(acc[q] + bias, 0.f));
  }
  bar_lds();
  if (w < 6) { // x_hat = sigmoid(e2 We3^T + be3)
    f32x4 acc = (f32x4){0.f,0.f,0.f,0.f};
    #pragma unroll
    for (int kt = 0; kt < 4; ++kt) {
      s16x8 a = *(const s16x8*)(e2b + li * 136 + kt * 32 + g * 8);
      acc = mfma16(a, w3[kt], acc);
    }
    int n = w * 16 + li;
    if (n < 88) {
      float bias = be3[n];
      #pragma unroll
      for (int q = 0; q < 4; ++q)
        xh[((size_t)b * 256 + s0 + g * 4 + q) * 88 + n] = sigmoid_f(acc[q] + bias);
    }
  }
}

// ---------- host ----------
extern "C" void kernel_launch(void* const* d_in, const int* in_sizes, int n_in,
                              void* d_out, int out_size, void* d_ws, size_t ws_size,
                              hipStream_t stream) {
  const float* x      = (const float*)d_in[0];
  const float* Wih_b  = (const float*)d_in[5];
  const float* Whh_b  = (const float*)d_in[6];
  const float* bih_b  = (const float*)d_in[7];
  const float* bhh_b  = (const float*)d_in[8];
  const float* Wc     = (const float*)d_in[9];
  const float* bc     = (const float*)d_in[10];
  const float* Wmu    = (const float*)d_in[11];
  const float* bmu    = (const float*)d_in[12];
  const float* Wsig   = (const float*)d_in[13];
  const float* bsig   = (const float*)d_in[14];
  const float* We1    = (const float*)d_in[15];
  const float* be1    = (const float*)d_in[16];
  const float* We2    = (const float*)d_in[17];
  const float* be2    = (const float*)d_in[18];
  const float* We3    = (const float*)d_in[19];
  const float* be3    = (const float*)d_in[20];
  const float* Wg1    = (const float*)d_in[21];
  const float* bg1    = (const float*)d_in[22];
  const float* Wg2    = (const float*)d_in[23];
  const float* bg2    = (const float*)d_in[24];
  const float* Wh1    = (const float*)d_in[25];
  const float* bh1    = (const float*)d_in[26];
  const float* Wh2    = (const float*)d_in[27];
  const float* bh2    = (const float*)d_in[28];
  const float* Wmg    = (const float*)d_in[29];
  const float* bmg    = (const float*)d_in[30];
  const float* Wsg    = (const float*)d_in[31];
  const float* bsg    = (const float*)d_in[32];
  const float* noise_inf = (const float*)d_in[33];
  const float* z0_gen    = (const float*)d_in[34];
  const float* noise_gen = (const float*)d_in[35];

  u16* ws16 = (u16*)d_ws;
  float* out = (float*)d_out;
  float* xh  = out;                 // (B,S,88)
  float* mui = out + 2883584;       // (B,S,100)
  float* sgi = out + 6160384;
  float* mug = out + 9437184;
  float* sgg = out + 12713984;
  u16* Zws = ws16 + U_XB;           // reuse xb region (dead after k_scan)

  k_pack<<<1079, 64, 0, stream>>>(ws16, Whh_b, Wc, Wmu, Wsig, Wg1, Wh1, Wg2, Wh2,
                                  Wmg, Wsg, We1, We2, We3, Wih_b);
  k_proj<<<2048, 256, 0, stream>>>(x, bih_b, ws16 + U_IN, ws16 + U_XB);
  k_scan<<<16, 448, 0, stream>>>(ws16 + U_RNN, ws16 + U_GA, ws16 + U_GB, ws16 + U_GC,
                                 ws16 + U_XB, ws16 + U_HR, bhh_b,
                                 z0_gen, bg1, bh1, bg2, bh2, bmg, bsg, noise_gen, mug, sgg);
  k_comb<<<8, 448, 0, stream>>>(ws16 + U_C1, ws16 + U_C2, ws16 + U_HR, bc, bmu, bsig,
                                noise_inf, Zws, mui, sgi);
  k_dec<<<2048, 448, 0, stream>>>(Zws, ws16 + U_E1, ws16 + U_E2, ws16 + U_E3,
                                  be1, be2, be3, xh);
}

// Round 4
// 1775.053 us; speedup vs baseline: 1.9809x; 1.1662x over previous
//
#include <hip/hip_runtime.h>
#include <math.h>

typedef float f32x4 __attribute__((ext_vector_type(4)));
typedef short s16x8 __attribute__((ext_vector_type(8)));
typedef unsigned short u16;

#define DI __device__ __forceinline__

// ---------- scalar helpers ----------
DI float bf2f(u16 h) { union { unsigned u; float f; } v; v.u = ((unsigned)h) << 16; return v.f; }
DI u16 f2bf(float f) {
  union { float f; unsigned u; } v; v.f = f;
  unsigned u = v.u;
  u += 0x7FFFu + ((u >> 16) & 1u);   // RNE
  return (u16)(u >> 16);
}
DI float tanh_fast(float x) {
  float e = __expf(2.f * x);
  return 1.f - 2.f / (e + 1.f);
}
DI float sigmoid_f(float x) { return 1.f / (1.f + __expf(-x)); }
DI float softplus_f(float x) { return fmaxf(x, 0.f) + log1pf(__expf(-fabsf(x))); }
DI f32x4 mfma16(s16x8 a, s16x8 b, f32x4 c) {
  return __builtin_amdgcn_mfma_f32_16x16x32_bf16(a, b, c, 0, 0, 0);
}
// Barrier with LDS drain only (global stores fire-and-forget; prefetch loads stay in flight)
DI void bar_lds() { asm volatile("s_waitcnt lgkmcnt(0)\n\ts_barrier" ::: "memory"); }
// fragment-major LDS address: A[row][k] lives at (k>>5)*512 + (((k>>3)&3)*16+row)*8 + (k&7)
DI int fa(int k, int row) { return ((k >> 5) << 9) + ((((k >> 3) & 3) * 16 + row) << 3) + (k & 7); }

union P16 { uint4 v[2]; u16 u[16]; };

// ---------- ws layout (u16 units) ----------
static constexpr size_t U_RNN = 0;          // Whh_b : KT=13 NT=28 (364 tiles)
static constexpr size_t U_C1  = 186368;     // Wc    : KT=4  NT=28 (112)
static constexpr size_t U_C2  = 243712;     // Wmu|Wsig : KT=13 NT=14 (182)
static constexpr size_t U_GA  = 336896;     // Wg1|Wh1  : KT=4  NT=28 (112)
static constexpr size_t U_GB  = 394240;     // Wg2|Wh2  : KT=7  NT=14 (98)
static constexpr size_t U_GC  = 444416;     // Wmg|Wsg  : KT=4  NT=14 (56)
static constexpr size_t U_E1  = 473088;     // We1 : KT=4 NT=7  (28)
static constexpr size_t U_E2  = 487424;     // We2 : KT=4 NT=7  (28)
static constexpr size_t U_E3  = 501760;     // We3 : KT=4 NT=6  (24)
static constexpr size_t U_IN  = 514048;     // Wih_b: KT=3 NT=25 (75)
static constexpr size_t U_SL  = 552448;     // slot buffer: [t][bid][thread(448)][16] u16
                                            // lifecycle per slot region (t,bid):
                                            //   k_proj writes xb -> rnn reads+overwrites with h
                                            //   -> comb reads h, ph2 overwrites [0,1792) with z
                                            //   -> k_dec reads z.   total 14,680,064 u16 (30.5MB end)

// ---------- K0: pack all weight matrices into MFMA B-fragment order ----------
__global__ void k_pack(u16* __restrict__ ws,
    const float* __restrict__ Whh_b, const float* __restrict__ Wc,
    const float* __restrict__ Wmu, const float* __restrict__ Wsig,
    const float* __restrict__ Wg1, const float* __restrict__ Wh1,
    const float* __restrict__ Wg2, const float* __restrict__ Wh2,
    const float* __restrict__ Wmg, const float* __restrict__ Wsg,
    const float* __restrict__ We1, const float* __restrict__ We2,
    const float* __restrict__ We3, const float* __restrict__ Wih_b)
{
  int r = blockIdx.x, l = threadIdx.x;
  int region, local;
  if      (r < 364)  { region = 0; local = r; }
  else if (r < 476)  { region = 1; local = r - 364; }
  else if (r < 658)  { region = 2; local = r - 476; }
  else if (r < 770)  { region = 3; local = r - 658; }
  else if (r < 868)  { region = 4; local = r - 770; }
  else if (r < 924)  { region = 5; local = r - 868; }
  else if (r < 952)  { region = 6; local = r - 924; }
  else if (r < 980)  { region = 7; local = r - 952; }
  else if (r < 1004) { region = 8; local = r - 980; }
  else               { region = 9; local = r - 1004; }

  int NT; size_t base;
  switch (region) {
    case 0: NT = 28; base = U_RNN; break;
    case 1: NT = 28; base = U_C1;  break;
    case 2: NT = 14; base = U_C2;  break;
    case 3: NT = 28; base = U_GA;  break;
    case 4: NT = 14; base = U_GB;  break;
    case 5: NT = 14; base = U_GC;  break;
    case 6: NT = 7;  base = U_E1;  break;
    case 7: NT = 7;  base = U_E2;  break;
    case 8: NT = 6;  base = U_E3;  break;
    default:NT = 25; base = U_IN;  break;
  }
  int kt = local / NT, nt = local % NT;
  u16* out = ws + base + ((size_t)local * 64 + l) * 8;
  #pragma unroll
  for (int e = 0; e < 8; ++e) {
    int k = kt * 32 + (l >> 4) * 8 + e;
    int n = nt * 16 + (l & 15);
    float v = 0.f;
    switch (region) {
      case 0: if (n < 400 && k < 400) v = Whh_b[n * 400 + k]; break;
      case 1: if (n < 400 && k < 100) v = Wc[n * 100 + k]; break;
      case 2: if (n < 112) { if (n < 100 && k < 400) v = Wmu[n * 400 + k]; }
              else { int m = n - 112; if (m < 100 && k < 400) v = Wsig[m * 400 + k]; } break;
      case 3: if (n < 208) { if (n < 200 && k < 100) v = Wg1[n * 100 + k]; }
              else if (n < 416) { int m = n - 208; if (m < 200 && k < 100) v = Wh1[m * 100 + k]; } break;
      case 4: if (n < 112) { if (n < 100 && k < 200) v = Wg2[n * 200 + k]; }
              else { int m = n - 112; if (m < 100 && k < 200) v = Wh2[m * 200 + k]; } break;
      case 5: if (n < 112) { if (n < 100 && k < 100) v = Wmg[n * 100 + k]; }
              else { int m = n - 112; if (m < 100 && k < 100) v = Wsg[m * 100 + k]; } break;
      case 6: if (n < 100 && k < 100) v = We1[n * 100 + k]; break;
      case 7: if (n < 100 && k < 100) v = We2[n * 100 + k]; break;
      case 8: if (n < 88  && k < 100) v = We3[n * 100 + k]; break;
      default:if (n < 400 && k < 88)  v = Wih_b[n * 88 + k]; break;
    }
    out[e] = f2bf(v);
  }
}

// ---------- K1: xb -> slot buffer, in rnn-consumer layout ----------
__global__ __launch_bounds__(256) void k_proj(
    const float* __restrict__ x, const float* __restrict__ bih_b,
    const u16* __restrict__ pk_in, u16* __restrict__ slot)
{
  __shared__ __align__(16) u16 x_lds[16][104];
  const int tid = threadIdx.x;
  const int cblk = blockIdx.x;
  const int b = cblk >> 4, s0 = (cblk & 15) << 4;
  const float* xg = x + (size_t)cblk * 16 * 88;
  for (int idx = tid; idx < 16 * 104; idx += 256) {
    int r = idx / 104, k = idx % 104;
    x_lds[r][k] = (k < 88) ? f2bf(xg[r * 88 + k]) : (u16)0;
  }
  __syncthreads();
  const int w = tid >> 6, l = tid & 63, g = l >> 4, li = l & 15;
  const int bid2 = b >> 4, r2 = b & 15, g2 = r2 >> 2, q2 = r2 & 3;
  s16x8 a[3];
  #pragma unroll
  for (int kt = 0; kt < 3; ++kt)
    a[kt] = *(const s16x8*)&x_lds[li][kt * 32 + g * 8];
  for (int nt = w; nt < 25; nt += 4) {
    f32x4 acc = (f32x4){0.f, 0.f, 0.f, 0.f};
    #pragma unroll
    for (int kt = 0; kt < 3; ++kt) {
      s16x8 bfr = *(const s16x8*)(pk_in + ((size_t)(kt * 25 + nt) * 64 + l) * 8);
      acc = mfma16(a[kt], bfr, acc);
    }
    int i = nt * 16 + li;
    float bias = bih_b[i];
    // consumer slot coords: t = s, thread = (i>>6)*64 + g2*16 + (i&15), elem = ((i>>4)&3)*4 + q2
    int thr = ((i >> 6) << 6) + (g2 << 4) + (i & 15);
    int elem = (((i >> 4) & 3) << 2) + q2;
    #pragma unroll
    for (int q = 0; q < 4; ++q) {
      int s = s0 + g * 4 + q;
      slot[((size_t)(s * 8 + bid2) * 448 + thr) * 16 + elem] = f2bf(acc[q] + bias);
    }
  }
}

// ---------- K2: fused backward-RNN -> comb (blocks 0-7) + generative scan (blocks 8-15) ----------
__global__ __launch_bounds__(448) void k_scan(
    const u16* __restrict__ pk_rnn, const u16* __restrict__ pk_c1, const u16* __restrict__ pk_c2,
    const u16* __restrict__ pk_gA, const u16* __restrict__ pk_gB, const u16* __restrict__ pk_gC,
    u16* __restrict__ slot, const float* __restrict__ bhh_b,
    const float* __restrict__ bc, const float* __restrict__ bmu, const float* __restrict__ bsig,
    const float* __restrict__ noise_inf,
    const float* __restrict__ z0g, const float* __restrict__ bg1, const float* __restrict__ bh1,
    const float* __restrict__ bg2, const float* __restrict__ bh2,
    const float* __restrict__ bmg, const float* __restrict__ bsg,
    const float* __restrict__ noise_gen,
    float* __restrict__ mui, float* __restrict__ sgi,
    float* __restrict__ mug, float* __restrict__ sgg)
{
  __shared__ __align__(16) u16 sm[56320];        // 112,640 B
  const int tid = threadIdx.x;
  const int w = tid >> 6, l = tid & 63, g = l >> 4, li = l & 15;
  const int bid = blockIdx.x;

  // defensive: no branch may ever see uninitialized LDS (round-3 bug class)
  {
    uint4 z4 = (uint4){0, 0, 0, 0};
    uint4* p = (uint4*)sm;
    for (int idx = tid; idx < 7040; idx += 448) p[idx] = z4;
  }
  __syncthreads();

  if (bid < 8) {
    const int b0 = bid * 16;
    { // ===== phase A: backward RNN, h = tanh(xb_t + h Whh^T + bhh), t = 255..0 =====
      u16* slab = sm;                 // Whh kt 10..12 : 3*28 = 84 tiles = 43008 u16
      u16* hbuf = sm + 43008;         // frag-major double buffer: 2 * 13*512
      {
        const uint4* src = (const uint4*)(pk_rnn + (size_t)10 * 28 * 512);
        uint4* dst = (uint4*)slab;
        for (int idx = tid; idx < 5376; idx += 448) dst[idx] = src[idx];   // FIX: 5376 (was 2688)
      }
      s16x8 wf[4][10];
      #pragma unroll
      for (int nt_l = 0; nt_l < 4; ++nt_l) {
        int nt = w * 4 + nt_l;
        #pragma unroll
        for (int kt = 0; kt < 10; ++kt)
          wf[nt_l][kt] = *(const s16x8*)(pk_rnn + ((size_t)(kt * 28 + nt) * 64 + l) * 8);
      }
      bool nv[4]; float bias_r[4];
      #pragma unroll
      for (int nt_l = 0; nt_l < 4; ++nt_l) {
        int n = (w * 4 + nt_l) * 16 + li;
        nv[nt_l] = (n < 400);
        bias_r[nt_l] = nv[nt_l] ? bhh_b[n] : 0.f;
      }
      P16 pf;
      {
        size_t base = ((size_t)(255 * 8 + bid) * 448 + w * 64 + l) * 16;
        pf.v[0] = *(const uint4*)(slot + base);
        pf.v[1] = *(const uint4*)(slot + base + 8);
      }
      __syncthreads();
      int cur = 0;
      for (int t = 0; t < 256; ++t) {
        const int tt = 255 - t;
        f32x4 acc[4];
        #pragma unroll
        for (int i = 0; i < 4; ++i) acc[i] = (f32x4){0.f, 0.f, 0.f, 0.f};
        const u16* hb = hbuf + cur * 6656;
        #pragma unroll
        for (int kt = 0; kt < 13; ++kt) {
          s16x8 a = *(const s16x8*)(hb + kt * 512 + l * 8);
          if (kt < 10) {
            #pragma unroll
            for (int nt_l = 0; nt_l < 4; ++nt_l) acc[nt_l] = mfma16(a, wf[nt_l][kt], acc[nt_l]);
          } else {
            #pragma unroll
            for (int nt_l = 0; nt_l < 4; ++nt_l) {
              s16x8 bfr = *(const s16x8*)(slab + ((size_t)((kt - 10) * 28 + w * 4 + nt_l) * 512) + l * 8);
              acc[nt_l] = mfma16(a, bfr, acc[nt_l]);
            }
          }
        }
        u16* hn = hbuf + (cur ^ 1) * 6656;
        P16 st; st.v[0] = (uint4){0,0,0,0}; st.v[1] = (uint4){0,0,0,0};
        #pragma unroll
        for (int nt_l = 0; nt_l < 4; ++nt_l) {
          if (nv[nt_l]) {
            int n = (w * 4 + nt_l) * 16 + li;
            #pragma unroll
            for (int q = 0; q < 4; ++q) {
              float v = acc[nt_l][q] + bf2f(pf.u[nt_l * 4 + q]) + bias_r[nt_l];
              u16 hv = f2bf(tanh_fast(v));
              hn[fa(n, 4 * g + q)] = hv;
              st.u[nt_l * 4 + q] = hv;
            }
          }
        }
        { // overwrite own slot (xb dead now) with h for comb
          size_t base = ((size_t)(tt * 8 + bid) * 448 + w * 64 + l) * 16;
          *(uint4*)(slot + base) = st.v[0];
          *(uint4*)(slot + base + 8) = st.v[1];
        }
        if (t < 255) {
          size_t nb = ((size_t)((tt - 1) * 8 + bid) * 448 + w * 64 + l) * 16;
          pf.v[0] = *(const uint4*)(slot + nb);
          pf.v[1] = *(const uint4*)(slot + nb + 8);
        }
        bar_lds();
        cur ^= 1;
      }
    }
    __syncthreads();   // full drain: h-slots visible to whole block; LDS reuse
    { // ===== phase B: comb scan =====
      u16* hbF = sm;          // frag-major h : 13*512
      u16* zbF = sm + 6656;   // frag-major z : 4*512
      for (int idx = tid; idx < 8704; idx += 448) sm[idx] = 0;
      s16x8 wC1[4][4], wMu[13], wSg[13];
      #pragma unroll
      for (int nt_l = 0; nt_l < 4; ++nt_l) {
        int nt = w * 4 + nt_l;
        #pragma unroll
        for (int kt = 0; kt < 4; ++kt)
          wC1[nt_l][kt] = *(const s16x8*)(pk_c1 + ((size_t)(kt * 28 + nt) * 64 + l) * 8);
      }
      #pragma unroll
      for (int kt = 0; kt < 13; ++kt) {
        wMu[kt] = *(const s16x8*)(pk_c2 + ((size_t)(kt * 14 + w) * 64 + l) * 8);
        wSg[kt] = *(const s16x8*)(pk_c2 + ((size_t)(kt * 14 + 7 + w) * 64 + l) * 8);
      }
      const int c = w * 16 + li;
      const bool cv = (c < 100);
      const float bmu_c = cv ? bmu[c] : 0.f;
      const float bsig_c = cv ? bsig[c] : 0.f;
      bool nv[4]; float bc_r[4];
      #pragma unroll
      for (int nt_l = 0; nt_l < 4; ++nt_l) {
        int n = (w * 4 + nt_l) * 16 + li;
        nv[nt_l] = (n < 400);
        bc_r[nt_l] = nv[nt_l] ? bc[n] : 0.f;
      }
      P16 pf;
      {
        size_t base = ((size_t)(0 * 8 + bid) * 448 + w * 64 + l) * 16;
        pf.v[0] = *(const uint4*)(slot + base);
        pf.v[1] = *(const uint4*)(slot + base + 8);
      }
      float pf_nz[4];
      #pragma unroll
      for (int q = 0; q < 4; ++q)
        pf_nz[q] = cv ? noise_inf[((size_t)0 * 128 + b0 + g * 4 + q) * 100 + c] : 0.f;
      __syncthreads();

      for (int t = 0; t < 256; ++t) {
        { // ph1: h = 0.5*(tanh(z Wc^T + bc) + hr_t)   [B-frags in regs]
          s16x8 az[4];
          #pragma unroll
          for (int kt = 0; kt < 4; ++kt)
            az[kt] = *(const s16x8*)(zbF + kt * 512 + l * 8);
          f32x4 a1[4];
          #pragma unroll
          for (int i = 0; i < 4; ++i) a1[i] = (f32x4){0.f, 0.f, 0.f, 0.f};
          #pragma unroll
          for (int kt = 0; kt < 4; ++kt) {
            #pragma unroll
            for (int nt_l = 0; nt_l < 4; ++nt_l) a1[nt_l] = mfma16(az[kt], wC1[nt_l][kt], a1[nt_l]);
          }
          #pragma unroll
          for (int nt_l = 0; nt_l < 4; ++nt_l) {
            if (nv[nt_l]) {
              int n = (w * 4 + nt_l) * 16 + li;
              #pragma unroll
              for (int q = 0; q < 4; ++q) {
                float hv = 0.5f * (tanh_fast(a1[nt_l][q] + bc_r[nt_l]) + bf2f(pf.u[nt_l * 4 + q]));
                hbF[fa(n, 4 * g + q)] = f2bf(hv);
              }
            }
          }
          if (t < 255) {
            size_t nb = ((size_t)((t + 1) * 8 + bid) * 448 + w * 64 + l) * 16;
            pf.v[0] = *(const uint4*)(slot + nb);
            pf.v[1] = *(const uint4*)(slot + nb + 8);
          }
        }
        bar_lds();
        { // ph2: mu / var / z; z also dropped into slot region for k_dec
          f32x4 am = (f32x4){0.f,0.f,0.f,0.f}, as_ = am;
          #pragma unroll
          for (int kt = 0; kt < 13; ++kt) {
            s16x8 a = *(const s16x8*)(hbF + kt * 512 + l * 8);
            am = mfma16(a, wMu[kt], am);
            as_ = mfma16(a, wSg[kt], as_);
          }
          #pragma unroll
          for (int q = 0; q < 4; ++q) {
            int r = g * 4 + q;
            float mu = am[q] + bmu_c;
            float va = softplus_f(as_[q] + bsig_c);
            if (cv) {
              size_t o = ((size_t)(b0 + r) * 256 + t) * 100 + c;
              mui[o] = mu;
              sgi[o] = va;
              float z = mu + sqrtf(va) * pf_nz[q];
              zbF[fa(c, r)] = f2bf(z);
              slot[(size_t)(t * 8 + bid) * 7168 + r * 112 + c] = f2bf(z);
            }
          }
          if (t < 255) {
            #pragma unroll
            for (int q = 0; q < 4; ++q)
              if (cv) pf_nz[q] = noise_inf[((size_t)(t + 1) * 128 + b0 + g * 4 + q) * 100 + c];
          }
        }
        bar_lds();
      }
    }
  } else {
    // ===== generative scan (tr_step) =====
    const int b0 = (bid - 8) * 16;
    u16* zbF  = sm;          // 4*512
    u16* rhbF = sm + 2048;   // 4*512
    u16* t1F  = sm + 4096;   // 7*512
    u16* t2F  = sm + 7680;   // 7*512 (end 11264)
    for (int idx = tid; idx < 2048; idx += 448) {
      int r = idx >> 7, c = idx & 127;
      zbF[fa(c, r)] = (c < 100) ? f2bf(z0g[(b0 + r) * 100 + c]) : (u16)0;
    }
    s16x8 wA[4][4], wBg[7], wBh[7], wCm[4], wCs[4];
    #pragma unroll
    for (int nt_l = 0; nt_l < 4; ++nt_l) {
      int nt = w * 4 + nt_l;
      #pragma unroll
      for (int kt = 0; kt < 4; ++kt)
        wA[nt_l][kt] = *(const s16x8*)(pk_gA + ((size_t)(kt * 28 + nt) * 64 + l) * 8);
    }
    #pragma unroll
    for (int kt = 0; kt < 7; ++kt) {
      wBg[kt] = *(const s16x8*)(pk_gB + ((size_t)(kt * 14 + w) * 64 + l) * 8);
      wBh[kt] = *(const s16x8*)(pk_gB + ((size_t)(kt * 14 + 7 + w) * 64 + l) * 8);
    }
    #pragma unroll
    for (int kt = 0; kt < 4; ++kt) {
      wCm[kt] = *(const s16x8*)(pk_gC + ((size_t)(kt * 14 + w) * 64 + l) * 8);
      wCs[kt] = *(const s16x8*)(pk_gC + ((size_t)(kt * 14 + 7 + w) * 64 + l) * 8);
    }
    const int c = w * 16 + li;
    const bool cv = (c < 100);
    const float bg2_c = cv ? bg2[c] : 0.f;
    const float bh2_c = cv ? bh2[c] : 0.f;
    const float bmg_c = cv ? bmg[c] : 0.f;
    const float bsg_c = cv ? bsg[c] : 0.f;
    float b1r[4];
    #pragma unroll
    for (int nt_l = 0; nt_l < 4; ++nt_l) {
      int n = (w * 4 + nt_l) * 16 + li;
      bool is1 = n < 208;
      int j = is1 ? n : n - 208;
      b1r[nt_l] = (n < 416 && j < 200) ? (is1 ? bg1[j] : bh1[j]) : 0.f;
    }
    float pfn[4];
    #pragma unroll
    for (int q = 0; q < 4; ++q)
      pfn[q] = cv ? noise_gen[((size_t)0 * 128 + b0 + g * 4 + q) * 100 + c] : 0.f;
    __syncthreads();

    for (int t = 0; t < 256; ++t) {
      s16x8 az[4];
      #pragma unroll
      for (int kt = 0; kt < 4; ++kt)
        az[kt] = *(const s16x8*)(zbF + kt * 512 + l * 8);
      { // ph1: t1 = relu(z Wg1^T + bg1) ; t2 = relu(z Wh1^T + bh1)  [B in regs]
        f32x4 a1[4];
        #pragma unroll
        for (int i = 0; i < 4; ++i) a1[i] = (f32x4){0.f, 0.f, 0.f, 0.f};
        #pragma unroll
        for (int kt = 0; kt < 4; ++kt) {
          #pragma unroll
          for (int nt_l = 0; nt_l < 4; ++nt_l) a1[nt_l] = mfma16(az[kt], wA[nt_l][kt], a1[nt_l]);
        }
        #pragma unroll
        for (int nt_l = 0; nt_l < 4; ++nt_l) {
          int n = (w * 4 + nt_l) * 16 + li;
          if (n < 416) {
            bool is1 = n < 208;
            int j = is1 ? n : n - 208;
            u16* dst = is1 ? t1F : t2F;
            #pragma unroll
            for (int q = 0; q < 4; ++q)
              dst[fa(j, 4 * g + q)] = f2bf(fmaxf(a1[nt_l][q] + b1r[nt_l], 0.f));
          }
        }
      }
      bar_lds();
      float muq[4];
      { // ph2: g, h_prop, m0; mu in-register; rh -> frags
        f32x4 ag = (f32x4){0.f,0.f,0.f,0.f}, ah = ag, am = ag;
        #pragma unroll
        for (int kt = 0; kt < 7; ++kt) {
          s16x8 x1 = *(const s16x8*)(t1F + kt * 512 + l * 8);
          ag = mfma16(x1, wBg[kt], ag);
        }
        #pragma unroll
        for (int kt = 0; kt < 7; ++kt) {
          s16x8 x2 = *(const s16x8*)(t2F + kt * 512 + l * 8);
          ah = mfma16(x2, wBh[kt], ah);
        }
        #pragma unroll
        for (int kt = 0; kt < 4; ++kt) am = mfma16(az[kt], wCm[kt], am);
        #pragma unroll
        for (int q = 0; q < 4; ++q) {
          int r = g * 4 + q;
          float gv = sigmoid_f(ag[q] + bg2_c);
          float hp = ah[q] + bh2_c;
          float m0 = am[q] + bmg_c;
          muq[q] = hp * gv + m0 * (1.f - gv);
          rhbF[fa(c, r)] = f2bf(fmaxf(hp, 0.f));   // zero for c>=100 (zero-padded weights)
          if (cv) mug[((size_t)(b0 + r) * 256 + t) * 100 + c] = muq[q];
        }
      }
      bar_lds();
      { // ph3: sigma = softplus(relu(h_prop) Wsg^T + bsg) ; z update
        f32x4 as2 = (f32x4){0.f,0.f,0.f,0.f};
        #pragma unroll
        for (int kt = 0; kt < 4; ++kt) {
          s16x8 xr = *(const s16x8*)(rhbF + kt * 512 + l * 8);
          as2 = mfma16(xr, wCs[kt], as2);
        }
        #pragma unroll
        for (int q = 0; q < 4; ++q) {
          int r = g * 4 + q;
          float sg = softplus_f(as2[q] + bsg_c);
          if (cv) {
            sgg[((size_t)(b0 + r) * 256 + t) * 100 + c] = sg;
            zbF[fa(c, r)] = f2bf(muq[q] + sqrtf(sg) * pfn[q]);
          }
        }
        if (t < 255) {
          #pragma unroll
          for (int q = 0; q < 4; ++q)
            if (cv) pfn[q] = noise_gen[((size_t)(t + 1) * 128 + b0 + g * 4 + q) * 100 + c];
        }
      }
      bar_lds();
    }
  }
}

// ---------- K3: decoder, parallel over (B,S); z read from slot regions ----------
__global__ __launch_bounds__(448) void k_dec(
    const u16* __restrict__ slot,
    const u16* __restrict__ pk_e1, const u16* __restrict__ pk_e2, const u16* __restrict__ pk_e3,
    const float* __restrict__ be1, const float* __restrict__ be2, const float* __restrict__ be3,
    float* __restrict__ xh)
{
  __shared__ __align__(16) u16 sm[3 * 2176];
  u16* zb = sm; u16* e1b = sm + 2176; u16* e2b = sm + 4352;
  const int tid = threadIdx.x;
  const int w = tid >> 6, l = tid & 63, g = l >> 4, li = l & 15;
  const int cc = blockIdx.x;
  const int b = cc >> 4, s0 = (cc & 15) << 4;
  const int bid2 = b >> 4, r2 = b & 15;

  s16x8 w1[4], w2[4], w3[4];
  #pragma unroll
  for (int kt = 0; kt < 4; ++kt) {
    w1[kt] = *(const s16x8*)(pk_e1 + ((size_t)(kt * 7 + w) * 64 + l) * 8);
    w2[kt] = *(const s16x8*)(pk_e2 + ((size_t)(kt * 7 + w) * 64 + l) * 8);
    if (w < 6) w3[kt] = *(const s16x8*)(pk_e3 + ((size_t)(kt * 6 + w) * 64 + l) * 8);
  }
  {
    for (int idx = tid; idx < 224; idx += 448) {
      int r = idx / 14, cj = idx % 14;
      size_t src = ((size_t)((s0 + r) * 8 + bid2)) * 7168 + r2 * 112 + cj * 8;
      *(uint4*)(zb + r * 136 + cj * 8) = *(const uint4*)(slot + src);
    }
    for (int idx = tid; idx < 3 * 384; idx += 448) {   // zero the 24-col pads
      int bi = idx / 384, j = idx % 384;
      (sm + bi * 2176)[(j / 24) * 136 + 112 + (j % 24)] = 0;
    }
  }
  __syncthreads();
  const int c = w * 16 + li;
  { // e1 = relu(z We1^T + be1)
    f32x4 acc = (f32x4){0.f,0.f,0.f,0.f};
    #pragma unroll
    for (int kt = 0; kt < 4; ++kt) {
      s16x8 a = *(const s16x8*)(zb + li * 136 + kt * 32 + g * 8);
      acc = mfma16(a, w1[kt], acc);
    }
    float bias = (c < 100) ? be1[c] : 0.f;
    #pragma unroll
    for (int q = 0; q < 4; ++q)
      e1b[(g * 4 + q) * 136 + c] = f2bf(fmaxf(acc[q] + bias, 0.f));
  }
  bar_lds();
  { // e2 = relu(e1 We2^T + be2)
    f32x4 acc = (f32x4){0.f,0.f,0.f,0.f};
    #pragma unroll
    for (int kt = 0; kt < 4; ++kt) {
      s16x8 a = *(const s16x8*)(e1b + li * 136 + kt * 32 + g * 8);
      acc = mfma16(a, w2[kt], acc);
    }
    float bias = (c < 100) ? be2[c] : 0.f;
    #pragma unroll
    for (int q = 0; q < 4; ++q)
      e2b[(g * 4 + q) * 136 + c] = f2bf(fmaxf(acc[q] + bias, 0.f));
  }
  bar_lds();
  if (w < 6) { // x_hat = sigmoid(e2 We3^T + be3)
    f32x4 acc = (f32x4){0.f,0.f,0.f,0.f};
    #pragma unroll
    for (int kt = 0; kt < 4; ++kt) {
      s16x8 a = *(const s16x8*)(e2b + li * 136 + kt * 32 + g * 8);
      acc = mfma16(a, w3[kt], acc);
    }
    int n = w * 16 + li;
    if (n < 88) {
      float bias = be3[n];
      #pragma unroll
      for (int q = 0; q < 4; ++q)
        xh[((size_t)b * 256 + s0 + g * 4 + q) * 88 + n] = sigmoid_f(acc[q] + bias);
    }
  }
}

// ---------- host ----------
extern "C" void kernel_launch(void* const* d_in, const int* in_sizes, int n_in,
                              void* d_out, int out_size, void* d_ws, size_t ws_size,
                              hipStream_t stream) {
  const float* x      = (const float*)d_in[0];
  const float* Wih_b  = (const float*)d_in[5];
  const float* Whh_b  = (const float*)d_in[6];
  const float* bih_b  = (const float*)d_in[7];
  const float* bhh_b  = (const float*)d_in[8];
  const float* Wc     = (const float*)d_in[9];
  const float* bc     = (const float*)d_in[10];
  const float* Wmu    = (const float*)d_in[11];
  const float* bmu    = (const float*)d_in[12];
  const float* Wsig   = (const float*)d_in[13];
  const float* bsig   = (const float*)d_in[14];
  const float* We1    = (const float*)d_in[15];
  const float* be1    = (const float*)d_in[16];
  const float* We2    = (const float*)d_in[17];
  const float* be2    = (const float*)d_in[18];
  const float* We3    = (const float*)d_in[19];
  const float* be3    = (const float*)d_in[20];
  const float* Wg1    = (const float*)d_in[21];
  const float* bg1    = (const float*)d_in[22];
  const float* Wg2    = (const float*)d_in[23];
  const float* bg2    = (const float*)d_in[24];
  const float* Wh1    = (const float*)d_in[25];
  const float* bh1    = (const float*)d_in[26];
  const float* Wh2    = (const float*)d_in[27];
  const float* bh2    = (const float*)d_in[28];
  const float* Wmg    = (const float*)d_in[29];
  const float* bmg    = (const float*)d_in[30];
  const float* Wsg    = (const float*)d_in[31];
  const float* bsg    = (const float*)d_in[32];
  const float* noise_inf = (const float*)d_in[33];
  const float* z0_gen    = (const float*)d_in[34];
  const float* noise_gen = (const float*)d_in[35];

  u16* ws16 = (u16*)d_ws;
  float* out = (float*)d_out;
  float* xh  = out;                 // (B,S,88)
  float* mui = out + 2883584;       // (B,S,100)
  float* sgi = out + 6160384;
  float* mug = out + 9437184;
  float* sgg = out + 12713984;
  u16* slot = ws16 + U_SL;

  k_pack<<<1079, 64, 0, stream>>>(ws16, Whh_b, Wc, Wmu, Wsig, Wg1, Wh1, Wg2, Wh2,
                                  Wmg, Wsg, We1, We2, We3, Wih_b);
  k_proj<<<2048, 256, 0, stream>>>(x, bih_b, ws16 + U_IN, slot);
  k_scan<<<16, 448, 0, stream>>>(ws16 + U_RNN, ws16 + U_C1, ws16 + U_C2,
                                 ws16 + U_GA, ws16 + U_GB, ws16 + U_GC,
                                 slot, bhh_b,
                                 bc, bmu, bsig, noise_inf,
                                 z0_gen, bg1, bh1, bg2, bh2, bmg, bsg, noise_gen,
                                 mui, sgi, mug, sgg);
  k_dec<<<2048, 448, 0, stream>>>(slot, ws16 + U_E1, ws16 + U_E2, ws16 + U_E3,
                                  be1, be2, be3, xh);
}